// Round 16
// baseline (437.774 us; speedup 1.0000x reference)
//
#include <hip/hip_runtime.h>
#include <hip/hip_bf16.h>

#define DIMN 1024
#define NH 16
#define HD 64
#define SEQ 2048
#define BATCH 2
#define BHN (BATCH*NH)        // 32
#define MROWS (BATCH*SEQ)     // 4096
#define KKEEP 409
#define SCALEF 0.125f
#define QROWS 16              // q-rows per block

typedef __attribute__((ext_vector_type(8))) short short8;
typedef __attribute__((ext_vector_type(4))) short short4v;
typedef __attribute__((ext_vector_type(4))) float f32x4;

#define MFMA(a,b,c) __builtin_amdgcn_mfma_f32_16x16x32_bf16(a,b,c,0,0,0)

// ---- Universal MFMA-fragment tile layout for [rows][1024] operands:
// T(m,k) = (m>>4)*16384 + (k>>5)*512 + (((k>>3)&3)*16 + (m&15))*8 + (k&7)

static __device__ __forceinline__ short f2bf(float f) {
    __hip_bfloat16 h = __float2bfloat16(f);
    return *reinterpret_cast<short*>(&h);
}
static __device__ __forceinline__ float bf2f(short s) {
    __hip_bfloat16 h = *reinterpret_cast<__hip_bfloat16*>(&s);
    return __bfloat162float(h);
}
static __device__ __forceinline__ short8 ld8(const short* p) {
    return *reinterpret_cast<const short8*>(p);
}
static __device__ __forceinline__ float keyf(unsigned u) {
    unsigned fu = (u & 0x80000000u) ? (u ^ 0x80000000u) : ~u;
    return __uint_as_float(fu);
}
static __device__ __forceinline__ size_t tidx(int row, int k) {
    return (size_t)(row >> 4) * 16384 + (size_t)(k >> 5) * 512
         + ((((k >> 3) & 3) * 16 + (row & 15)) * 8) + (k & 7);
}

// ---------------- K0: ALL fp32->bf16 conversions in one launch --------------
static __device__ __forceinline__ void conv_hilo_body(
    const float* in, short* hi, short* lo, int rows) {
    const int total = rows * 256;
    for (int idx = blockIdx.x * blockDim.x + threadIdx.x; idx < total;
         idx += gridDim.x * blockDim.x) {
        const int row = idx >> 8;
        const int k = (idx & 255) * 4;
        float4 v = *reinterpret_cast<const float4*>(in + (size_t)row * DIMN + k);
        short4v h, l;
        #pragma unroll
        for (int j = 0; j < 4; ++j) {
            float f = (&v.x)[j];
            short hb = f2bf(f);
            h[j] = hb;
            l[j] = f2bf(f - bf2f(hb));
        }
        const size_t o = tidx(row, k);
        *reinterpret_cast<short4v*>(hi + o) = h;
        *reinterpret_cast<short4v*>(lo + o) = l;
    }
}
static __device__ __forceinline__ void conv_bf16_body(
    const float* in, short* out, int rows) {
    const int total = rows * 256;
    for (int idx = blockIdx.x * blockDim.x + threadIdx.x; idx < total;
         idx += gridDim.x * blockDim.x) {
        const int row = idx >> 8;
        const int k = (idx & 255) * 4;
        float4 v = *reinterpret_cast<const float4*>(in + (size_t)row * DIMN + k);
        short4v o;
        o[0] = f2bf(v.x); o[1] = f2bf(v.y); o[2] = f2bf(v.z); o[3] = f2bf(v.w);
        *reinterpret_cast<short4v*>(out + tidx(row, k)) = o;
    }
}
__global__ void conv_all(
    const float* __restrict__ x, const float* __restrict__ wq,
    const float* __restrict__ wk, const float* __restrict__ wv,
    const float* __restrict__ wo,
    short* __restrict__ xhi, short* __restrict__ xlo,
    short* __restrict__ wqh, short* __restrict__ wql,
    short* __restrict__ wkh, short* __restrict__ wkl,
    short* __restrict__ wvb, short* __restrict__ wob)
{
    switch (blockIdx.y) {
        case 0: conv_hilo_body(x,  xhi, xlo, MROWS); break;
        case 1: conv_hilo_body(wq, wqh, wql, DIMN);  break;
        case 2: conv_hilo_body(wk, wkh, wkl, DIMN);  break;
        case 3: conv_bf16_body(wv, wvb, DIMN);       break;
        default: conv_bf16_body(wo, wob, DIMN);      break;
    }
}

// ---------------- K1: Q/K/V projections, one launch (z=0 q, 1 k, 2 v) ------
__global__ __launch_bounds__(256) void qkv_mfma(
    const short* __restrict__ xh, const short* __restrict__ xl,
    const short* __restrict__ wqh, const short* __restrict__ wql, const float* __restrict__ bq,
    const short* __restrict__ wkh, const short* __restrict__ wkl, const float* __restrict__ bk,
    const short* __restrict__ wvb, const float* __restrict__ bv,
    short* __restrict__ qhi, short* __restrict__ qlo,
    short* __restrict__ khi, short* __restrict__ klo,
    short* __restrict__ vt)
{
    const int z = blockIdx.z;
    const int tid  = threadIdx.x;
    const int wv_  = tid >> 6, lane = tid & 63;
    const int r    = lane & 15, kg = lane >> 4;
    const int m_base = blockIdx.x * 128 + wv_ * 32;
    const int n_base = blockIdx.y * 64;
    const int mtile0 = blockIdx.x * 8 + wv_ * 2;
    const int ntile0 = blockIdx.y * 4;
    const int h = blockIdx.y;

    f32x4 acc[2][4] = {};

    if (z < 2) {
        const short* wh = z ? wkh : wqh;
        const short* wl = z ? wkl : wql;
        const float* bias = z ? bk : bq;
        short* dhi = z ? khi : qhi;
        short* dlo = z ? klo : qlo;

        for (int ks = 0; ks < 32; ++ks) {
            short8 ah0 = ld8(xh + (size_t)mtile0 * 16384 + ks * 512 + lane * 8);
            short8 al0 = ld8(xl + (size_t)mtile0 * 16384 + ks * 512 + lane * 8);
            short8 ah1 = ld8(xh + (size_t)(mtile0 + 1) * 16384 + ks * 512 + lane * 8);
            short8 al1 = ld8(xl + (size_t)(mtile0 + 1) * 16384 + ks * 512 + lane * 8);
            #pragma unroll
            for (int nf = 0; nf < 4; ++nf) {
                short8 bh = ld8(wh + (size_t)(ntile0 + nf) * 16384 + ks * 512 + lane * 8);
                short8 bl = ld8(wl + (size_t)(ntile0 + nf) * 16384 + ks * 512 + lane * 8);
                acc[0][nf] = MFMA(ah0, bh, acc[0][nf]);
                acc[0][nf] = MFMA(ah0, bl, acc[0][nf]);
                acc[0][nf] = MFMA(al0, bh, acc[0][nf]);
                acc[1][nf] = MFMA(ah1, bh, acc[1][nf]);
                acc[1][nf] = MFMA(ah1, bl, acc[1][nf]);
                acc[1][nf] = MFMA(al1, bh, acc[1][nf]);
            }
        }

        #pragma unroll
        for (int mf = 0; mf < 2; ++mf)
            #pragma unroll
            for (int nf = 0; nf < 4; ++nf)
                #pragma unroll
                for (int i = 0; i < 4; ++i) {
                    const int m  = m_base + mf * 16 + kg * 4 + i;
                    const int nn = n_base + nf * 16 + r;
                    const float val = acc[mf][nf][i] + bias[nn];
                    const int b_ = m >> 11, s = m & 2047;
                    const int hd = nf * 16 + r;
                    const size_t idx = (size_t)(b_ * NH + h) * 131072
                        + (size_t)(s >> 4) * 1024 + (hd >> 5) * 512
                        + ((((hd >> 3) & 3) * 16 + (s & 15)) * 8) + (hd & 7);
                    const short hb = f2bf(val);
                    dhi[idx] = hb;
                    dlo[idx] = f2bf(val - bf2f(hb));
                }
    } else {
        for (int ks = 0; ks < 32; ++ks) {
            short8 ah0 = ld8(xh + (size_t)mtile0 * 16384 + ks * 512 + lane * 8);
            short8 al0 = ld8(xl + (size_t)mtile0 * 16384 + ks * 512 + lane * 8);
            short8 ah1 = ld8(xh + (size_t)(mtile0 + 1) * 16384 + ks * 512 + lane * 8);
            short8 al1 = ld8(xl + (size_t)(mtile0 + 1) * 16384 + ks * 512 + lane * 8);
            #pragma unroll
            for (int nf = 0; nf < 4; ++nf) {
                short8 b = ld8(wvb + (size_t)(ntile0 + nf) * 16384 + ks * 512 + lane * 8);
                acc[0][nf] = MFMA(ah0, b, acc[0][nf]);
                acc[0][nf] = MFMA(al0, b, acc[0][nf]);
                acc[1][nf] = MFMA(ah1, b, acc[1][nf]);
                acc[1][nf] = MFMA(al1, b, acc[1][nf]);
            }
        }

        #pragma unroll
        for (int mf = 0; mf < 2; ++mf)
            #pragma unroll
            for (int nf = 0; nf < 4; ++nf)
                #pragma unroll
                for (int i = 0; i < 4; ++i) {
                    const int m  = m_base + mf * 16 + kg * 4 + i;
                    const int nn = n_base + nf * 16 + r;
                    const float val = acc[mf][nf][i] + bv[nn];
                    const int b_ = m >> 11, s = m & 2047;
                    const int hd = nf * 16 + r;
                    const size_t idx = (size_t)(b_ * NH + h) * 131072
                        + (size_t)(hd >> 4) * 32768 + (size_t)(s >> 5) * 512
                        + ((((s >> 3) & 3) * 16 + (hd & 15)) * 8) + (s & 7);
                    vt[idx] = f2bf(val);
                }
    }
}

// ---------------- K2: fused scores + exact top-k + softmax + PV ------------
// 512-col chunks; LDS 64KB -> 2 blocks/CU; XCD-pinned. NEW vs R15:
// (a) V prefetched to registers — VLOAD(0) issues before the register-only
//     radix phase so V latency hides under ~1-2k cycles of VALU;
// (b) STAGE groups 8 K-loads ahead of their 12 MFMAs (explicit ILP);
// (c) s_setprio(1) around MFMA clusters (T5). Bit-identical arithmetic.
__global__ __launch_bounds__(512, 4) void fused_attn(
    const short* __restrict__ qh, const short* __restrict__ ql,
    const short* __restrict__ kh, const short* __restrict__ kl,
    const short* __restrict__ vtb, float* __restrict__ attn,
    short* __restrict__ ctxt)
{
    __shared__ __align__(16) char smem[65536];
    // Phase A: CB0 fp32[16][512] @0 (32KB), CB1 @32768
    // Phase C: E0 bf16[16][512] @0 (16KB), E1 @16384, CT fp32[16][64] @32768
    float* CT = (float*)(smem + 32768);

    const int tid = threadIdx.x;
    const int w   = tid >> 6, lane = tid & 63;
    const int r   = lane & 15, kg = lane >> 4;

    // XCD-pinned mapping
    const int bid  = blockIdx.x;
    const int xcd  = bid & 7;
    const int slot = bid >> 3;
    const int bh   = xcd + 8 * (slot >> 7);
    const int qt   = slot & 127;
    const int q0   = qt * QROWS;

    // ---- Phase A: S = SCALE*Q K^T, 4 chunks of 512 cols, pipelined ----
    const size_t qtbase = (size_t)bh * 131072 + (size_t)qt * 1024 + lane * 8;
    short8 a0h = ld8(qh + qtbase),       a0l = ld8(ql + qtbase);
    short8 a1h = ld8(qh + qtbase + 512), a1l = ld8(ql + qtbase + 512);

    unsigned u[2][32];

    auto STAGE = [&](int c, float* buf) {
        #pragma unroll
        for (int half = 0; half < 2; ++half) {
            short8 L[2][4];
            #pragma unroll
            for (int t2 = 0; t2 < 2; ++t2) {
                const int tt = half * 2 + t2;
                const int stile = c * 32 + w + 8 * tt;
                const size_t tb = (size_t)bh * 131072 + (size_t)stile * 1024 + lane * 8;
                L[t2][0] = ld8(kh + tb);
                L[t2][1] = ld8(kl + tb);
                L[t2][2] = ld8(kh + tb + 512);
                L[t2][3] = ld8(kl + tb + 512);
            }
            __builtin_amdgcn_s_setprio(1);
            #pragma unroll
            for (int t2 = 0; t2 < 2; ++t2) {
                const int tt = half * 2 + t2;
                f32x4 accA = {0.f, 0.f, 0.f, 0.f};
                f32x4 accB = {0.f, 0.f, 0.f, 0.f};
                accA = MFMA(a0h, L[t2][0], accA);
                accB = MFMA(a1h, L[t2][2], accB);
                accA = MFMA(a0h, L[t2][1], accA);
                accB = MFMA(a1h, L[t2][3], accB);
                accA = MFMA(a0l, L[t2][0], accA);
                accB = MFMA(a1l, L[t2][2], accB);
                const int j0c = (w + 8 * tt) * 16;
                #pragma unroll
                for (int i = 0; i < 4; ++i)
                    buf[(kg * 4 + i) * 512 + j0c + r] = (accA[i] + accB[i]) * SCALEF;
            }
            __builtin_amdgcn_s_setprio(0);
        }
    };

    STAGE(0, (float*)smem);
    __syncthreads();
    #pragma unroll
    for (int c = 0; c < 4; ++c) {
        float* cur = (float*)(smem + ((c & 1) ? 32768 : 0));
        float* nxt = (float*)(smem + ((c & 1) ? 0 : 32768));
        if (c + 1 < 4) STAGE(c + 1, nxt);
        #pragma unroll
        for (int rr = 0; rr < 2; ++rr) {
            const float* src = cur + (w + 8 * rr) * 512;
            #pragma unroll
            for (int g = 0; g < 2; ++g) {
                f32x4 v4 = *reinterpret_cast<const f32x4*>(src + g * 256 + lane * 4);
                #pragma unroll
                for (int q_ = 0; q_ < 4; ++q_) {
                    unsigned fu = __float_as_uint(v4[q_]);
                    u[rr][c * 8 + g * 4 + q_] =
                        (fu & 0x80000000u) ? ~fu : (fu | 0x80000000u);
                }
            }
        }
        __syncthreads();
    }

    // ---- V prefetch for chunk 0: latency hides under the radix phase ----
    const int khf = w >> 2;
    short8 vr[8];
    auto VLOAD = [&](int c) {
        const size_t vbase = (size_t)bh * 131072 + (size_t)(w & 3) * 32768
                           + (size_t)(c * 16 + khf * 8) * 512 + lane * 8;
        #pragma unroll
        for (int ks = 0; ks < 8; ++ks) vr[ks] = ld8(vtb + vbase + ks * 512);
    };
    VLOAD(0);

    // ---- Phase B: early-exit exact radix top-k + softmax (regs only) ----
    float inv[2];
    #pragma unroll
    for (int rr = 0; rr < 2; ++rr) {
        unsigned cur = 0;
        for (int bit = 31; bit >= 0; --bit) {
            const unsigned cand = cur | (1u << bit);
            int cnt = 0;
            #pragma unroll
            for (int jj = 0; jj < 32; ++jj)
                cnt += __popcll(__ballot(u[rr][jj] >= cand));
            if (cnt >= KKEEP) {
                cur = cand;
                if (cnt == KKEEP) break;
            }
        }
        unsigned mu = 0;
        #pragma unroll
        for (int jj = 0; jj < 32; ++jj) mu = (u[rr][jj] > mu) ? u[rr][jj] : mu;
        #pragma unroll
        for (int off = 32; off; off >>= 1) {
            unsigned o = (unsigned)__shfl_xor((int)mu, off);
            mu = (o > mu) ? o : mu;
        }
        const float m = keyf(mu);
        float denom = 0.f;
        #pragma unroll
        for (int jj = 0; jj < 32; ++jj) {
            const unsigned ue = u[rr][jj];
            const float e = (ue >= cur) ? __expf(keyf(ue) - m) : 0.f;
            u[rr][jj] = __float_as_uint(e);
            denom += e;
        }
        #pragma unroll
        for (int off = 32; off; off >>= 1) denom += __shfl_xor(denom, off);
        inv[rr] = 1.0f / denom;
    }

    // ---- Phase C: 4x 512-col chunks; E double-buffered; V from regs ----
    const int swzw = (w & 7) << 4;
    const int swzr = (r & 7) << 4;
    f32x4 acc = {0.f, 0.f, 0.f, 0.f};

    auto EWRITE = [&](int c, char* Ebase) {
        #pragma unroll
        for (int rr = 0; rr < 2; ++rr) {
            const int row = w + 8 * rr;
            const float iv = inv[rr];
            #pragma unroll
            for (int g = 0; g < 2; ++g) {
                short4v pb;
                pb[0] = f2bf(__uint_as_float(u[rr][c * 8 + g * 4 + 0]) * iv);
                pb[1] = f2bf(__uint_as_float(u[rr][c * 8 + g * 4 + 1]) * iv);
                pb[2] = f2bf(__uint_as_float(u[rr][c * 8 + g * 4 + 2]) * iv);
                pb[3] = f2bf(__uint_as_float(u[rr][c * 8 + g * 4 + 3]) * iv);
                *reinterpret_cast<short4v*>(
                    Ebase + row * 1024 + ((g * 512 + lane * 8) ^ swzw)) = pb;
            }
        }
    };
    auto PVSTEP = [&](int c, const char* Ebase) {
        const char* Eb2 = Ebase + r * 1024;
        __builtin_amdgcn_s_setprio(1);
        #pragma unroll
        for (int ks = 0; ks < 8; ++ks) {
            const int kk = khf * 8 + ks;
            short8 pa = *reinterpret_cast<const short8*>(
                Eb2 + ((kk * 64 + kg * 16) ^ swzr));
            acc = MFMA(pa, vr[ks], acc);
        }
        __builtin_amdgcn_s_setprio(0);
    };

    EWRITE(0, smem);
    __syncthreads();
    #pragma unroll
    for (int c = 0; c < 4; ++c) {
        char* curE = smem + ((c & 1) ? 16384 : 0);
        char* nxtE = smem + ((c & 1) ? 0 : 16384);
        if (c + 1 < 4) EWRITE(c + 1, nxtE);
        PVSTEP(c, curE);
        if (c + 1 < 4) VLOAD(c + 1);   // issue next V; hides under sync+EWRITE
        __syncthreads();
    }

    // ---- CT exchange, write ctx in universal tile layout ----
    const int dt = w & 3;
    if (khf == 1) {
        #pragma unroll
        for (int i = 0; i < 4; ++i) CT[(kg * 4 + i) * 64 + dt * 16 + r] = acc[i];
    }
    __syncthreads();
    if (khf == 0) {
        const int b_ = bh >> 4, h = bh & 15;
        const size_t base = (size_t)(b_ * 128 + qt) * 16384
                          + (size_t)(h * 2 + (dt >> 1)) * 512;
        #pragma unroll
        for (int i = 0; i < 4; ++i) {
            const int lrow = kg * 4 + i;
            const float val = acc[i] + CT[lrow * 64 + dt * 16 + r];
            ctxt[base + ((((dt * 2 + (r >> 3)) & 3) * 16 + lrow) * 8) + (r & 7)]
                = f2bf(val);
        }
    }

    // ---- attn stream-out: after the last barrier, fire-and-forget ----
    #pragma unroll
    for (int rr = 0; rr < 2; ++rr) {
        const int row = w + 8 * rr;
        const float iv = inv[rr];
        float* arow = attn + ((size_t)bh * SEQ + q0 + row) * SEQ + lane * 4;
        #pragma unroll
        for (int c = 0; c < 4; ++c)
            #pragma unroll
            for (int g = 0; g < 2; ++g) {
                f32x4 pv;
                pv[0] = __uint_as_float(u[rr][c * 8 + g * 4 + 0]) * iv;
                pv[1] = __uint_as_float(u[rr][c * 8 + g * 4 + 1]) * iv;
                pv[2] = __uint_as_float(u[rr][c * 8 + g * 4 + 2]) * iv;
                pv[3] = __uint_as_float(u[rr][c * 8 + g * 4 + 3]) * iv;
                __builtin_nontemporal_store(
                    pv, reinterpret_cast<f32x4*>(arow + c * 512 + g * 256));
            }
    }
}

// ---------------- K3: out = ctx @ wo^T + bo, tiled A and B ------------------
__global__ __launch_bounds__(256) void out_mfma(
    const short* __restrict__ ctxt, const short* __restrict__ wob,
    const float* __restrict__ bo, float* __restrict__ out)
{
    const int tid = threadIdx.x;
    const int w_  = tid >> 6, lane = tid & 63;
    const int r   = lane & 15, kg = lane >> 4;
    const int m_base = blockIdx.x * 128 + w_ * 32;
    const int n_base = blockIdx.y * 64;
    const int mtile0 = blockIdx.x * 8 + w_ * 2;
    const int ntile0 = blockIdx.y * 4;

    f32x4 acc[2][4] = {};

    for (int ks = 0; ks < 32; ++ks) {
        short8 a0 = ld8(ctxt + (size_t)mtile0 * 16384 + ks * 512 + lane * 8);
        short8 a1 = ld8(ctxt + (size_t)(mtile0 + 1) * 16384 + ks * 512 + lane * 8);
        #pragma unroll
        for (int nf = 0; nf < 4; ++nf) {
            short8 b = ld8(wob + (size_t)(ntile0 + nf) * 16384 + ks * 512 + lane * 8);
            acc[0][nf] = MFMA(a0, b, acc[0][nf]);
            acc[1][nf] = MFMA(a1, b, acc[1][nf]);
        }
    }

    #pragma unroll
    for (int mf = 0; mf < 2; ++mf)
        #pragma unroll
        for (int nf = 0; nf < 4; ++nf)
            #pragma unroll
            for (int i = 0; i < 4; ++i) {
                const int m  = m_base + mf * 16 + kg * 4 + i;
                const int nn = n_base + nf * 16 + r;
                out[(size_t)m * DIMN + nn] = acc[mf][nf][i] + bo[nn];
            }
}

extern "C" void kernel_launch(void* const* d_in, const int* in_sizes, int n_in,
                              void* d_out, int out_size, void* d_ws, size_t ws_size,
                              hipStream_t stream) {
    const float* x  = (const float*)d_in[0];
    const float* wq = (const float*)d_in[1];
    const float* bq = (const float*)d_in[2];
    const float* wk = (const float*)d_in[3];
    const float* bk = (const float*)d_in[4];
    const float* wv = (const float*)d_in[5];
    const float* bv = (const float*)d_in[6];
    const float* wo = (const float*)d_in[7];
    const float* bo = (const float*)d_in[8];

    float* out  = (float*)d_out;
    float* attn = out + (size_t)MROWS * DIMN;   // 512 MB region, written by fused_attn

    // --- scratch that dies before fused_attn runs: lives in the attn region ---
    short* xhi = (short*)attn;
    short* xlo = xhi + (size_t)MROWS * DIMN;
    short* wqh = xlo + (size_t)MROWS * DIMN;
    short* wql = wqh + (size_t)DIMN * DIMN;
    short* wkh = wql + (size_t)DIMN * DIMN;
    short* wkl = wkh + (size_t)DIMN * DIMN;
    short* wvb = wkl + (size_t)DIMN * DIMN;

    // --- scratch that must survive into/past fused_attn: lives in d_ws ---
    const size_t QKV = (size_t)BHN * SEQ * HD;  // 4,194,304
    short* qhi = (short*)d_ws;
    short* qlo = qhi + QKV;
    short* khi = qlo + QKV;
    short* klo = khi + QKV;
    short* vt  = klo + QKV;
    short* ctx = vt  + QKV;
    short* wob = ctx + QKV;

    conv_all<<<dim3(512, 5), 256, 0, stream>>>(
        x, wq, wk, wv, wo, xhi, xlo, wqh, wql, wkh, wkl, wvb, wob);

    qkv_mfma<<<dim3(MROWS / 128, DIMN / 64, 3), 256, 0, stream>>>(
        xhi, xlo, wqh, wql, bq, wkh, wkl, bk, wvb, bv,
        qhi, qlo, khi, klo, vt);

    fused_attn<<<dim3(SEQ / QROWS * BHN), 512, 0, stream>>>(
        qhi, qlo, khi, klo, vt, attn, ctx);

    out_mfma<<<dim3(MROWS / 128, DIMN / 64), 256, 0, stream>>>(ctx, wob, bo, out);
}

// Round 17
// 408.543 us; speedup vs baseline: 1.0716x; 1.0716x over previous
//
#include <hip/hip_runtime.h>
#include <hip/hip_bf16.h>

#define DIMN 1024
#define NH 16
#define HD 64
#define SEQ 2048
#define BATCH 2
#define BHN (BATCH*NH)        // 32
#define MROWS (BATCH*SEQ)     // 4096
#define KKEEP 409
#define SCALEF 0.125f
#define QROWS 16              // q-rows per block

typedef __attribute__((ext_vector_type(8))) short short8;
typedef __attribute__((ext_vector_type(4))) short short4v;
typedef __attribute__((ext_vector_type(4))) float f32x4;

#define MFMA(a,b,c) __builtin_amdgcn_mfma_f32_16x16x32_bf16(a,b,c,0,0,0)

// ---- Universal MFMA-fragment tile layout for [rows][1024] operands:
// T(m,k) = (m>>4)*16384 + (k>>5)*512 + (((k>>3)&3)*16 + (m&15))*8 + (k&7)

static __device__ __forceinline__ short f2bf(float f) {
    __hip_bfloat16 h = __float2bfloat16(f);
    return *reinterpret_cast<short*>(&h);
}
static __device__ __forceinline__ float bf2f(short s) {
    __hip_bfloat16 h = *reinterpret_cast<__hip_bfloat16*>(&s);
    return __bfloat162float(h);
}
static __device__ __forceinline__ short8 ld8(const short* p) {
    return *reinterpret_cast<const short8*>(p);
}
static __device__ __forceinline__ float keyf(unsigned u) {
    unsigned fu = (u & 0x80000000u) ? (u ^ 0x80000000u) : ~u;
    return __uint_as_float(fu);
}
static __device__ __forceinline__ size_t tidx(int row, int k) {
    return (size_t)(row >> 4) * 16384 + (size_t)(k >> 5) * 512
         + ((((k >> 3) & 3) * 16 + (row & 15)) * 8) + (k & 7);
}

// ---------------- K0: ALL fp32->bf16 conversions in one launch --------------
static __device__ __forceinline__ void conv_hilo_body(
    const float* in, short* hi, short* lo, int rows) {
    const int total = rows * 256;
    for (int idx = blockIdx.x * blockDim.x + threadIdx.x; idx < total;
         idx += gridDim.x * blockDim.x) {
        const int row = idx >> 8;
        const int k = (idx & 255) * 4;
        float4 v = *reinterpret_cast<const float4*>(in + (size_t)row * DIMN + k);
        short4v h, l;
        #pragma unroll
        for (int j = 0; j < 4; ++j) {
            float f = (&v.x)[j];
            short hb = f2bf(f);
            h[j] = hb;
            l[j] = f2bf(f - bf2f(hb));
        }
        const size_t o = tidx(row, k);
        *reinterpret_cast<short4v*>(hi + o) = h;
        *reinterpret_cast<short4v*>(lo + o) = l;
    }
}
static __device__ __forceinline__ void conv_bf16_body(
    const float* in, short* out, int rows) {
    const int total = rows * 256;
    for (int idx = blockIdx.x * blockDim.x + threadIdx.x; idx < total;
         idx += gridDim.x * blockDim.x) {
        const int row = idx >> 8;
        const int k = (idx & 255) * 4;
        float4 v = *reinterpret_cast<const float4*>(in + (size_t)row * DIMN + k);
        short4v o;
        o[0] = f2bf(v.x); o[1] = f2bf(v.y); o[2] = f2bf(v.z); o[3] = f2bf(v.w);
        *reinterpret_cast<short4v*>(out + tidx(row, k)) = o;
    }
}
__global__ void conv_all(
    const float* __restrict__ x, const float* __restrict__ wq,
    const float* __restrict__ wk, const float* __restrict__ wv,
    const float* __restrict__ wo,
    short* __restrict__ xhi, short* __restrict__ xlo,
    short* __restrict__ wqh, short* __restrict__ wql,
    short* __restrict__ wkh, short* __restrict__ wkl,
    short* __restrict__ wvb, short* __restrict__ wob)
{
    switch (blockIdx.y) {
        case 0: conv_hilo_body(x,  xhi, xlo, MROWS); break;
        case 1: conv_hilo_body(wq, wqh, wql, DIMN);  break;
        case 2: conv_hilo_body(wk, wkh, wkl, DIMN);  break;
        case 3: conv_bf16_body(wv, wvb, DIMN);       break;
        default: conv_bf16_body(wo, wob, DIMN);      break;
    }
}

// ---------------- K1: Q/K/V projections, one launch (z=0 q, 1 k, 2 v) ------
__global__ __launch_bounds__(256) void qkv_mfma(
    const short* __restrict__ xh, const short* __restrict__ xl,
    const short* __restrict__ wqh, const short* __restrict__ wql, const float* __restrict__ bq,
    const short* __restrict__ wkh, const short* __restrict__ wkl, const float* __restrict__ bk,
    const short* __restrict__ wvb, const float* __restrict__ bv,
    short* __restrict__ qhi, short* __restrict__ qlo,
    short* __restrict__ khi, short* __restrict__ klo,
    short* __restrict__ vt)
{
    const int z = blockIdx.z;
    const int tid  = threadIdx.x;
    const int wv_  = tid >> 6, lane = tid & 63;
    const int r    = lane & 15, kg = lane >> 4;
    const int m_base = blockIdx.x * 128 + wv_ * 32;
    const int n_base = blockIdx.y * 64;
    const int mtile0 = blockIdx.x * 8 + wv_ * 2;
    const int ntile0 = blockIdx.y * 4;
    const int h = blockIdx.y;

    f32x4 acc[2][4] = {};

    if (z < 2) {
        const short* wh = z ? wkh : wqh;
        const short* wl = z ? wkl : wql;
        const float* bias = z ? bk : bq;
        short* dhi = z ? khi : qhi;
        short* dlo = z ? klo : qlo;

        for (int ks = 0; ks < 32; ++ks) {
            short8 ah0 = ld8(xh + (size_t)mtile0 * 16384 + ks * 512 + lane * 8);
            short8 al0 = ld8(xl + (size_t)mtile0 * 16384 + ks * 512 + lane * 8);
            short8 ah1 = ld8(xh + (size_t)(mtile0 + 1) * 16384 + ks * 512 + lane * 8);
            short8 al1 = ld8(xl + (size_t)(mtile0 + 1) * 16384 + ks * 512 + lane * 8);
            #pragma unroll
            for (int nf = 0; nf < 4; ++nf) {
                short8 bh = ld8(wh + (size_t)(ntile0 + nf) * 16384 + ks * 512 + lane * 8);
                short8 bl = ld8(wl + (size_t)(ntile0 + nf) * 16384 + ks * 512 + lane * 8);
                acc[0][nf] = MFMA(ah0, bh, acc[0][nf]);
                acc[0][nf] = MFMA(ah0, bl, acc[0][nf]);
                acc[0][nf] = MFMA(al0, bh, acc[0][nf]);
                acc[1][nf] = MFMA(ah1, bh, acc[1][nf]);
                acc[1][nf] = MFMA(ah1, bl, acc[1][nf]);
                acc[1][nf] = MFMA(al1, bh, acc[1][nf]);
            }
        }

        #pragma unroll
        for (int mf = 0; mf < 2; ++mf)
            #pragma unroll
            for (int nf = 0; nf < 4; ++nf)
                #pragma unroll
                for (int i = 0; i < 4; ++i) {
                    const int m  = m_base + mf * 16 + kg * 4 + i;
                    const int nn = n_base + nf * 16 + r;
                    const float val = acc[mf][nf][i] + bias[nn];
                    const int b_ = m >> 11, s = m & 2047;
                    const int hd = nf * 16 + r;
                    const size_t idx = (size_t)(b_ * NH + h) * 131072
                        + (size_t)(s >> 4) * 1024 + (hd >> 5) * 512
                        + ((((hd >> 3) & 3) * 16 + (s & 15)) * 8) + (hd & 7);
                    const short hb = f2bf(val);
                    dhi[idx] = hb;
                    dlo[idx] = f2bf(val - bf2f(hb));
                }
    } else {
        for (int ks = 0; ks < 32; ++ks) {
            short8 ah0 = ld8(xh + (size_t)mtile0 * 16384 + ks * 512 + lane * 8);
            short8 al0 = ld8(xl + (size_t)mtile0 * 16384 + ks * 512 + lane * 8);
            short8 ah1 = ld8(xh + (size_t)(mtile0 + 1) * 16384 + ks * 512 + lane * 8);
            short8 al1 = ld8(xl + (size_t)(mtile0 + 1) * 16384 + ks * 512 + lane * 8);
            #pragma unroll
            for (int nf = 0; nf < 4; ++nf) {
                short8 b = ld8(wvb + (size_t)(ntile0 + nf) * 16384 + ks * 512 + lane * 8);
                acc[0][nf] = MFMA(ah0, b, acc[0][nf]);
                acc[0][nf] = MFMA(al0, b, acc[0][nf]);
                acc[1][nf] = MFMA(ah1, b, acc[1][nf]);
                acc[1][nf] = MFMA(al1, b, acc[1][nf]);
            }
        }

        #pragma unroll
        for (int mf = 0; mf < 2; ++mf)
            #pragma unroll
            for (int nf = 0; nf < 4; ++nf)
                #pragma unroll
                for (int i = 0; i < 4; ++i) {
                    const int m  = m_base + mf * 16 + kg * 4 + i;
                    const int nn = n_base + nf * 16 + r;
                    const float val = acc[mf][nf][i] + bv[nn];
                    const int b_ = m >> 11, s = m & 2047;
                    const int hd = nf * 16 + r;
                    const size_t idx = (size_t)(b_ * NH + h) * 131072
                        + (size_t)(hd >> 4) * 32768 + (size_t)(s >> 5) * 512
                        + ((((s >> 3) & 3) * 16 + (hd & 15)) * 8) + (s & 7);
                    vt[idx] = f2bf(val);
                }
    }
}

// ---------------- K2: fused scores + exact top-k + softmax + PV ------------
// 512-col chunks (4 per row): 12 barriers/block. LDS 64KB -> 2 blocks/CU.
// XCD-pinned 1-D grid. R15 configuration (R16's reg-prefetch reverted:
// it spilled to scratch, +180MB writes).
__global__ __launch_bounds__(512, 4) void fused_attn(
    const short* __restrict__ qh, const short* __restrict__ ql,
    const short* __restrict__ kh, const short* __restrict__ kl,
    const short* __restrict__ vtb, float* __restrict__ attn,
    short* __restrict__ ctxt)
{
    __shared__ __align__(16) char smem[65536];
    // Phase A: CB0 fp32[16][512] @0 (32KB), CB1 @32768
    // Phase C: E0 bf16[16][512] @0 (16KB), E1 @16384, CT fp32[16][64] @32768
    float* CT = (float*)(smem + 32768);

    const int tid = threadIdx.x;
    const int w   = tid >> 6, lane = tid & 63;
    const int r   = lane & 15, kg = lane >> 4;

    // XCD-pinned mapping
    const int bid  = blockIdx.x;
    const int xcd  = bid & 7;
    const int slot = bid >> 3;
    const int bh   = xcd + 8 * (slot >> 7);
    const int qt   = slot & 127;
    const int q0   = qt * QROWS;

    // ---- Phase A: S = SCALE*Q K^T, 4 chunks of 512 cols, pipelined ----
    const size_t qtbase = (size_t)bh * 131072 + (size_t)qt * 1024 + lane * 8;
    short8 a0h = ld8(qh + qtbase),       a0l = ld8(ql + qtbase);
    short8 a1h = ld8(qh + qtbase + 512), a1l = ld8(ql + qtbase + 512);

    unsigned u[2][32];

    auto STAGE = [&](int c, float* buf) {
        #pragma unroll
        for (int tt = 0; tt < 4; ++tt) {
            const int stile = c * 32 + w + 8 * tt;
            const size_t tb = (size_t)bh * 131072 + (size_t)stile * 1024 + lane * 8;
            short8 b0h = ld8(kh + tb);
            short8 b0l = ld8(kl + tb);
            short8 b1h = ld8(kh + tb + 512);
            short8 b1l = ld8(kl + tb + 512);
            f32x4 accA = {0.f, 0.f, 0.f, 0.f};
            f32x4 accB = {0.f, 0.f, 0.f, 0.f};
            accA = MFMA(a0h, b0h, accA);
            accB = MFMA(a1h, b1h, accB);
            accA = MFMA(a0h, b0l, accA);
            accB = MFMA(a1h, b1l, accB);
            accA = MFMA(a0l, b0h, accA);
            accB = MFMA(a1l, b1h, accB);
            const int j0c = (w + 8 * tt) * 16;
            #pragma unroll
            for (int i = 0; i < 4; ++i)
                buf[(kg * 4 + i) * 512 + j0c + r] = (accA[i] + accB[i]) * SCALEF;
        }
    };

    STAGE(0, (float*)smem);
    __syncthreads();
    #pragma unroll
    for (int c = 0; c < 4; ++c) {
        float* cur = (float*)(smem + ((c & 1) ? 32768 : 0));
        float* nxt = (float*)(smem + ((c & 1) ? 0 : 32768));
        if (c + 1 < 4) STAGE(c + 1, nxt);
        #pragma unroll
        for (int rr = 0; rr < 2; ++rr) {
            const float* src = cur + (w + 8 * rr) * 512;
            #pragma unroll
            for (int g = 0; g < 2; ++g) {
                f32x4 v4 = *reinterpret_cast<const f32x4*>(src + g * 256 + lane * 4);
                #pragma unroll
                for (int q_ = 0; q_ < 4; ++q_) {
                    unsigned fu = __float_as_uint(v4[q_]);
                    u[rr][c * 8 + g * 4 + q_] =
                        (fu & 0x80000000u) ? ~fu : (fu | 0x80000000u);
                }
            }
        }
        __syncthreads();
    }

    // ---- Phase B: early-exit exact radix top-k + softmax (regs only) ----
    float inv[2];
    #pragma unroll
    for (int rr = 0; rr < 2; ++rr) {
        unsigned cur = 0;
        for (int bit = 31; bit >= 0; --bit) {
            const unsigned cand = cur | (1u << bit);
            int cnt = 0;
            #pragma unroll
            for (int jj = 0; jj < 32; ++jj)
                cnt += __popcll(__ballot(u[rr][jj] >= cand));
            if (cnt >= KKEEP) {
                cur = cand;
                if (cnt == KKEEP) break;
            }
        }
        unsigned mu = 0;
        #pragma unroll
        for (int jj = 0; jj < 32; ++jj) mu = (u[rr][jj] > mu) ? u[rr][jj] : mu;
        #pragma unroll
        for (int off = 32; off; off >>= 1) {
            unsigned o = (unsigned)__shfl_xor((int)mu, off);
            mu = (o > mu) ? o : mu;
        }
        const float m = keyf(mu);
        float denom = 0.f;
        #pragma unroll
        for (int jj = 0; jj < 32; ++jj) {
            const unsigned ue = u[rr][jj];
            const float e = (ue >= cur) ? __expf(keyf(ue) - m) : 0.f;
            u[rr][jj] = __float_as_uint(e);
            denom += e;
        }
        #pragma unroll
        for (int off = 32; off; off >>= 1) denom += __shfl_xor(denom, off);
        inv[rr] = 1.0f / denom;
    }

    // ---- Phase C: 4x 512-col chunks; E double-buffered; LDS writes only ----
    const int khf = w >> 2;
    const int swzw = (w & 7) << 4;
    const int swzr = (r & 7) << 4;
    f32x4 acc = {0.f, 0.f, 0.f, 0.f};

    auto EWRITE = [&](int c, char* Ebase) {
        #pragma unroll
        for (int rr = 0; rr < 2; ++rr) {
            const int row = w + 8 * rr;
            const float iv = inv[rr];
            #pragma unroll
            for (int g = 0; g < 2; ++g) {
                short4v pb;
                pb[0] = f2bf(__uint_as_float(u[rr][c * 8 + g * 4 + 0]) * iv);
                pb[1] = f2bf(__uint_as_float(u[rr][c * 8 + g * 4 + 1]) * iv);
                pb[2] = f2bf(__uint_as_float(u[rr][c * 8 + g * 4 + 2]) * iv);
                pb[3] = f2bf(__uint_as_float(u[rr][c * 8 + g * 4 + 3]) * iv);
                *reinterpret_cast<short4v*>(
                    Ebase + row * 1024 + ((g * 512 + lane * 8) ^ swzw)) = pb;
            }
        }
    };
    auto PVSTEP = [&](int c, const char* Ebase) {
        const size_t vbase = (size_t)bh * 131072 + (size_t)(w & 3) * 32768
                           + (size_t)(c * 16 + khf * 8) * 512 + lane * 8;
        const char* Eb2 = Ebase + r * 1024;
        #pragma unroll
        for (int ks = 0; ks < 8; ++ks) {
            const int kk = khf * 8 + ks;
            short8 pa = *reinterpret_cast<const short8*>(
                Eb2 + ((kk * 64 + kg * 16) ^ swzr));
            short8 vb = ld8(vtb + vbase + ks * 512);
            acc = MFMA(pa, vb, acc);
        }
    };

    EWRITE(0, smem);
    __syncthreads();
    #pragma unroll
    for (int c = 0; c < 4; ++c) {
        char* curE = smem + ((c & 1) ? 16384 : 0);
        char* nxtE = smem + ((c & 1) ? 0 : 16384);
        if (c + 1 < 4) EWRITE(c + 1, nxtE);
        PVSTEP(c, curE);
        __syncthreads();
    }

    // ---- CT exchange, write ctx in universal tile layout ----
    const int dt = w & 3;
    if (khf == 1) {
        #pragma unroll
        for (int i = 0; i < 4; ++i) CT[(kg * 4 + i) * 64 + dt * 16 + r] = acc[i];
    }
    __syncthreads();
    if (khf == 0) {
        const int b_ = bh >> 4, h = bh & 15;
        const size_t base = (size_t)(b_ * 128 + qt) * 16384
                          + (size_t)(h * 2 + (dt >> 1)) * 512;
        #pragma unroll
        for (int i = 0; i < 4; ++i) {
            const int lrow = kg * 4 + i;
            const float val = acc[i] + CT[lrow * 64 + dt * 16 + r];
            ctxt[base + ((((dt * 2 + (r >> 3)) & 3) * 16 + lrow) * 8) + (r & 7)]
                = f2bf(val);
        }
    }

    // ---- attn stream-out: after the last barrier, fire-and-forget ----
    #pragma unroll
    for (int rr = 0; rr < 2; ++rr) {
        const int row = w + 8 * rr;
        const float iv = inv[rr];
        float* arow = attn + ((size_t)bh * SEQ + q0 + row) * SEQ + lane * 4;
        #pragma unroll
        for (int c = 0; c < 4; ++c)
            #pragma unroll
            for (int g = 0; g < 2; ++g) {
                f32x4 pv;
                pv[0] = __uint_as_float(u[rr][c * 8 + g * 4 + 0]) * iv;
                pv[1] = __uint_as_float(u[rr][c * 8 + g * 4 + 1]) * iv;
                pv[2] = __uint_as_float(u[rr][c * 8 + g * 4 + 2]) * iv;
                pv[3] = __uint_as_float(u[rr][c * 8 + g * 4 + 3]) * iv;
                __builtin_nontemporal_store(
                    pv, reinterpret_cast<f32x4*>(arow + c * 512 + g * 256));
            }
    }
}

// ---------------- K3: out = ctx @ wo^T + bo, tiled A and B ------------------
__global__ __launch_bounds__(256) void out_mfma(
    const short* __restrict__ ctxt, const short* __restrict__ wob,
    const float* __restrict__ bo, float* __restrict__ out)
{
    const int tid = threadIdx.x;
    const int w_  = tid >> 6, lane = tid & 63;
    const int r   = lane & 15, kg = lane >> 4;
    const int m_base = blockIdx.x * 128 + w_ * 32;
    const int n_base = blockIdx.y * 64;
    const int mtile0 = blockIdx.x * 8 + w_ * 2;
    const int ntile0 = blockIdx.y * 4;

    f32x4 acc[2][4] = {};

    for (int ks = 0; ks < 32; ++ks) {
        short8 a0 = ld8(ctxt + (size_t)mtile0 * 16384 + ks * 512 + lane * 8);
        short8 a1 = ld8(ctxt + (size_t)(mtile0 + 1) * 16384 + ks * 512 + lane * 8);
        #pragma unroll
        for (int nf = 0; nf < 4; ++nf) {
            short8 b = ld8(wob + (size_t)(ntile0 + nf) * 16384 + ks * 512 + lane * 8);
            acc[0][nf] = MFMA(a0, b, acc[0][nf]);
            acc[1][nf] = MFMA(a1, b, acc[1][nf]);
        }
    }

    #pragma unroll
    for (int mf = 0; mf < 2; ++mf)
        #pragma unroll
        for (int nf = 0; nf < 4; ++nf)
            #pragma unroll
            for (int i = 0; i < 4; ++i) {
                const int m  = m_base + mf * 16 + kg * 4 + i;
                const int nn = n_base + nf * 16 + r;
                out[(size_t)m * DIMN + nn] = acc[mf][nf][i] + bo[nn];
            }
}

extern "C" void kernel_launch(void* const* d_in, const int* in_sizes, int n_in,
                              void* d_out, int out_size, void* d_ws, size_t ws_size,
                              hipStream_t stream) {
    const float* x  = (const float*)d_in[0];
    const float* wq = (const float*)d_in[1];
    const float* bq = (const float*)d_in[2];
    const float* wk = (const float*)d_in[3];
    const float* bk = (const float*)d_in[4];
    const float* wv = (const float*)d_in[5];
    const float* bv = (const float*)d_in[6];
    const float* wo = (const float*)d_in[7];
    const float* bo = (const float*)d_in[8];

    float* out  = (float*)d_out;
    float* attn = out + (size_t)MROWS * DIMN;   // 512 MB region, written by fused_attn

    // --- scratch that dies before fused_attn runs: lives in the attn region ---
    short* xhi = (short*)attn;
    short* xlo = xhi + (size_t)MROWS * DIMN;
    short* wqh = xlo + (size_t)MROWS * DIMN;
    short* wql = wqh + (size_t)DIMN * DIMN;
    short* wkh = wql + (size_t)DIMN * DIMN;
    short* wkl = wkh + (size_t)DIMN * DIMN;
    short* wvb = wkl + (size_t)DIMN * DIMN;

    // --- scratch that must survive into/past fused_attn: lives in d_ws ---
    const size_t QKV = (size_t)BHN * SEQ * HD;  // 4,194,304
    short* qhi = (short*)d_ws;
    short* qlo = qhi + QKV;
    short* khi = qlo + QKV;
    short* klo = khi + QKV;
    short* vt  = klo + QKV;
    short* ctx = vt  + QKV;
    short* wob = ctx + QKV;

    conv_all<<<dim3(512, 5), 256, 0, stream>>>(
        x, wq, wk, wv, wo, xhi, xlo, wqh, wql, wkh, wkl, wvb, wob);

    qkv_mfma<<<dim3(MROWS / 128, DIMN / 64, 3), 256, 0, stream>>>(
        xhi, xlo, wqh, wql, bq, wkh, wkl, bk, wvb, bv,
        qhi, qlo, khi, klo, vt);

    fused_attn<<<dim3(SEQ / QROWS * BHN), 512, 0, stream>>>(
        qhi, qlo, khi, klo, vt, attn, ctx);

    out_mfma<<<dim3(MROWS / 128, DIMN / 64), 256, 0, stream>>>(ctx, wob, bo, out);
}